// Round 5
// baseline (339.177 us; speedup 1.0000x reference)
//
#include <hip/hip_runtime.h>
#include <stdint.h>

#define NLAYERS 3
#define NQ 8
#define DIM 256          // 2^NQ
#define KDIM 512         // 2*DIM (real+imag)
#define BM 32            // batch rows per block
#define NBLK (131072 / BM)
#define AST 72           // A LDS row stride in bf16 (64 + 8 pad)

typedef float  f32x4  __attribute__((ext_vector_type(4)));
typedef __bf16 bf16x8 __attribute__((ext_vector_type(8)));

__device__ __forceinline__ unsigned short f2bf(float f){
    union { float f; uint32_t u; } v; v.f = f;
    uint32_t u = v.u;
    u += 0x7fffu + ((u >> 16) & 1u);   // round-to-nearest-even
    return (unsigned short)(u >> 16);
}

__device__ __forceinline__ float2 cmul(float2 a, float2 b){
    return make_float2(a.x*b.x - a.y*b.y, a.x*b.y + a.y*b.x);
}

// ---------------------------------------------------------------------------
// Kernel 1: build G (256x512 bf16, row-major [n][k]) from params.
// Block j simulates the circuit on basis state e_j in LDS.  (validated R1-R4)
// ---------------------------------------------------------------------------
__global__ __launch_bounds__(256) void build_g_kernel(const float* __restrict__ params,
                                                      unsigned short* __restrict__ G){
    __shared__ float2 st[2][DIM];
    __shared__ float2 gm[NLAYERS*NQ][4];   // U0a,U0b,U1a,U1b per gate
    const int j = blockIdx.x;
    const int i = threadIdx.x;

    if (i < NLAYERS*NQ){
        const float* pp = params + i*3;
        float hx = 0.5f*pp[0], hy = 0.5f*pp[1], hz = 0.5f*pp[2];
        float cx = cosf(hx), sx = sinf(hx);
        float cy = cosf(hy), sy = sinf(hy);
        float cz = cosf(hz), sz = sinf(hz);
        float2 ezm = make_float2(cz, -sz), ezp = make_float2(cz, sz);
        float2 m00 = make_float2( cy*cx,  sy*sx);
        float2 m01 = make_float2(-sy*cx, -cy*sx);
        float2 m10 = make_float2( sy*cx, -cy*sx);
        float2 m11 = make_float2( cy*cx, -sy*sx);
        gm[i][0] = cmul(ezm, m00);
        gm[i][1] = cmul(ezm, m01);
        gm[i][2] = cmul(ezp, m10);
        gm[i][3] = cmul(ezp, m11);
    }

    int psrc = i;                          // composed CNOT-ring permutation
    #pragma unroll
    for (int q = NQ-1; q >= 0; --q){
        int c  = 7 - q;
        int tb = 7 - ((q + 1) & 7);
        psrc = ((psrc >> c) & 1) ? (psrc ^ (1 << tb)) : psrc;
    }

    int cur = 0;
    st[0][i] = make_float2(i == j ? 1.0f : 0.0f, 0.0f);
    __syncthreads();

    for (int l = 0; l < NLAYERS; ++l){
        for (int q = 0; q < NQ; ++q){
            float2 U0a = gm[l*NQ+q][0], U0b = gm[l*NQ+q][1];
            float2 U1a = gm[l*NQ+q][2], U1b = gm[l*NQ+q][3];
            int p  = 7 - q;
            int bs = (i >> p) & 1;
            int i0 = i & ~(1 << p), i1 = i | (1 << p);
            float2 a0 = st[cur][i0], a1 = st[cur][i1];
            float2 ua = bs ? U1a : U0a;
            float2 ub = bs ? U1b : U0b;
            float2 r;
            r.x = ua.x*a0.x - ua.y*a0.y + ub.x*a1.x - ub.y*a1.y;
            r.y = ua.x*a0.y + ua.y*a0.x + ub.x*a1.y + ub.y*a1.x;
            st[cur ^ 1][i] = r;
            cur ^= 1;
            __syncthreads();
        }
        float2 r = st[cur][psrc];
        st[cur ^ 1][i] = r;
        cur ^= 1;
        __syncthreads();
    }

    const int m = i & 127;
    float2 a = st[cur][m];
    unsigned short lo, hi;
    if (i < 128){ lo = f2bf(a.x); hi = f2bf(-a.y); }   // Wre | -Wim
    else        { lo = f2bf(a.y); hi = f2bf( a.x); }   // Wim |  Wre
    G[(size_t)i*KDIM + j]        = lo;
    G[(size_t)i*KDIM + j + DIM]  = hi;
}

// ---------------------------------------------------------------------------
// Kernel 2: out[m] = || G * [sr_m ; si_m] ||^2
// Streaming structure: BM=32 rows/block, 4096 blocks, 4 blocks/CU.
// A double-buffered in tiny LDS (2 x 4.6 KB); loads for phase kc+1 issued at
// the TOP of phase kc so each block keeps ~8 KB outstanding for the whole
// phase; 4 staggered blocks/CU -> near-continuous per-CU outstanding bytes.
// B (G) fragments read directly from L2-resident global inside the MFMA loop
// (no staging, no barrier dependency). Low VGPR by construction (~100).
// ---------------------------------------------------------------------------
__global__ __launch_bounds__(256, 4) void qform_kernel(const float* __restrict__ sr,
                                                       const float* __restrict__ si,
                                                       const unsigned short* __restrict__ G,
                                                       float* __restrict__ out){
    __shared__ unsigned short As[2][BM * AST];   // 2 x 4608 B
    __shared__ float red[4][BM];                 // 512 B

    const int tid  = threadIdx.x;
    const int lane = tid & 63;
    const int w    = tid >> 6;        // wave 0..3 -> n-slice [w*64, w*64+64)
    const int l15  = lane & 15;
    const int quad = lane >> 4;       // 0..3
    const int srow = tid >> 3;        // staging row 0..31
    const int sseg = tid & 7;         // staging segment (8 fp32)
    const size_t mbase = (size_t)blockIdx.x * BM;

    float4 L0, L1;                    // in-flight A loads (8 fp32/thread)

    #define ISSUE_A(kc1)                                                       \
        {                                                                      \
            const float* gp = (((kc1) < 4) ? sr : si)                          \
                + (mbase + srow)*(size_t)DIM + (((kc1) & 3)*64 + sseg*8);      \
            L0 = ((const float4*)gp)[0];                                       \
            L1 = ((const float4*)gp)[1];                                       \
        }

    #define WRITE_A(buf)                                                       \
        {                                                                      \
            uint4 pk;                                                          \
            pk.x = f2bf(L0.x) | ((uint32_t)f2bf(L0.y) << 16);                  \
            pk.y = f2bf(L0.z) | ((uint32_t)f2bf(L0.w) << 16);                  \
            pk.z = f2bf(L1.x) | ((uint32_t)f2bf(L1.y) << 16);                  \
            pk.w = f2bf(L1.z) | ((uint32_t)f2bf(L1.w) << 16);                  \
            *(uint4*)&As[buf][srow*AST + sseg*8] = pk;                         \
        }

    // prologue: stage phase 0
    ISSUE_A(0);
    WRITE_A(0);

    f32x4 acc[2][4];
    const f32x4 vzero = {0.0f, 0.0f, 0.0f, 0.0f};
    #pragma unroll
    for (int ii = 0; ii < 2; ++ii)
        #pragma unroll
        for (int jj = 0; jj < 4; ++jj)
            acc[ii][jj] = vzero;

    // per-lane B base: row n = w*64 + jj*16 + l15, col = kc*64 + ks*32 + quad*8
    const unsigned short* gB = G + (size_t)(w*64 + l15)*KDIM + quad*8;

    __syncthreads();

    for (int kc = 0; kc < 8; ++kc){
        if (kc < 7) ISSUE_A(kc + 1);          // in flight across this phase

        const int buf = kc & 1;
        #pragma unroll
        for (int ks = 0; ks < 2; ++ks){
            bf16x8 a[2], b[4];
            #pragma unroll
            for (int jj = 0; jj < 4; ++jj)
                b[jj] = *(const bf16x8*)(gB + (size_t)jj*16*KDIM + kc*64 + ks*32);
            #pragma unroll
            for (int ii = 0; ii < 2; ++ii)
                a[ii] = *(const bf16x8*)&As[buf][(ii*16 + l15)*AST + ks*32 + quad*8];
            #pragma unroll
            for (int ii = 0; ii < 2; ++ii)
                #pragma unroll
                for (int jj = 0; jj < 4; ++jj)
                    acc[ii][jj] = __builtin_amdgcn_mfma_f32_16x16x32_bf16(
                        a[ii], b[jj], acc[ii][jj], 0, 0, 0);
        }

        if (kc < 7) WRITE_A((kc + 1) & 1);    // waits the prefetch, fills other buf
        __syncthreads();
    }

    // ---- epilogue: out[m] = sum_n Y[m][n]^2
    // C/D layout: n = jj*16 + l15, m = ii*16 + quad*4 + r
    #pragma unroll
    for (int ii = 0; ii < 2; ++ii)
        #pragma unroll
        for (int r = 0; r < 4; ++r){
            float t = 0.0f;
            #pragma unroll
            for (int jj = 0; jj < 4; ++jj){ float v = acc[ii][jj][r]; t += v*v; }
            t += __shfl_xor(t, 1);
            t += __shfl_xor(t, 2);
            t += __shfl_xor(t, 4);
            t += __shfl_xor(t, 8);
            if (l15 == 0) red[w][ii*16 + quad*4 + r] = t;
        }
    __syncthreads();
    if (tid < BM){
        float o = red[0][tid] + red[1][tid] + red[2][tid] + red[3][tid];
        out[mbase + tid] = o;
    }

    #undef ISSUE_A
    #undef WRITE_A
}

extern "C" void kernel_launch(void* const* d_in, const int* in_sizes, int n_in,
                              void* d_out, int out_size, void* d_ws, size_t ws_size,
                              hipStream_t stream){
    const float* params = (const float*)d_in[0];
    const float* sr     = (const float*)d_in[1];
    const float* si     = (const float*)d_in[2];
    unsigned short* G   = (unsigned short*)d_ws;   // 256*512*2 = 256 KB
    float* out          = (float*)d_out;

    build_g_kernel<<<dim3(DIM), dim3(256), 0, stream>>>(params, G);
    qform_kernel<<<dim3(NBLK), dim3(256), 0, stream>>>(sr, si, G, out);
}